// Round 1
// baseline (1453.847 us; speedup 1.0000x reference)
//
#include <hip/hip_runtime.h>

// IPAttnProcessor cross-modal fused pipeline for MI355X (gfx950).
// All GEMM-shaped math uses split-bf16 MFMA emulation of fp32:
//   x = hi + lo (two bf16), A*B ~= Ahi*Bhi + Ahi*Blo + Alo*Bhi  (error ~2^-16 rel)
// Workspace usage: attn buffer (16384*1280 f32) + kv text proj (4*77*2560) +
// ip proj (4*4*2560)  ~= 88 MB. Q is staged in d_out (overwritten by final GEMM).

typedef __attribute__((ext_vector_type(8))) short short8;
typedef __attribute__((ext_vector_type(4))) float f32x4;
typedef __attribute__((ext_vector_type(4))) unsigned short us4;

__device__ __forceinline__ unsigned short bhi(float x){
  return (unsigned short)(__builtin_bit_cast(unsigned int, x) >> 16);
}
__device__ __forceinline__ float fromb(unsigned short h){
  unsigned int u = ((unsigned int)h) << 16;
  return __builtin_bit_cast(float, u);
}
// truncation split: x = hi + lo + err, |err| <= 2^-16 |x|
__device__ __forceinline__ void split2(float x, unsigned short& h, unsigned short& l){
  h = bhi(x);
  l = bhi(x - fromb(h));
}
__device__ __forceinline__ f32x4 mf16(short8 a, short8 b, f32x4 c){
  return __builtin_amdgcn_mfma_f32_16x16x32_bf16(a, b, c, 0, 0, 0);
}

union Frag { short8 s; unsigned long long u[2]; };

// ---------------------------------------------------------------------------
// Split-bf16 GEMM: C[z] = A[z] @ B (+bias) (+res). 128x128 tile, BK=32,
// 256 threads = 4 waves in 2x2 arrangement, each wave 64x64 (4x4 frags).
// B is selected between B0/B1 at column nsplit (for concatenated [Wk|Wv]).
// B is transposed into LDS at staging so fragment reads are contiguous.
// ---------------------------------------------------------------------------
template<int BIAS, int RES>
__global__ __launch_bounds__(256)
void gemm_split(const float* __restrict__ A, int lda, long strideAz, int M,
                const float* __restrict__ B0, const float* __restrict__ B1,
                int nsplit, int ldb,
                float* __restrict__ C, int ldc, long strideCz,
                int K,
                const float* __restrict__ bias,
                const float* __restrict__ res, int ldres)
{
  const int bn = blockIdx.x * 128;
  const int bm = blockIdx.y * 128;
  A += (long)blockIdx.z * strideAz;
  C += (long)blockIdx.z * strideCz;
  const float* B = B0; int bcol = bn;
  if (bn >= nsplit){ B = B1; bcol = bn - nsplit; }

  const int tid = threadIdx.x;
  const int lane = tid & 63, w = tid >> 6;
  const int wm = w >> 1, wn = w & 1;
  const int r16 = lane & 15, g = lane >> 4;

  // stride 36 shorts = 72B: 16-lane frag reads land on 16 distinct bank pairs
  __shared__ unsigned short Ah[128][36], Al[128][36];
  __shared__ unsigned short Bh[128][36], Bl[128][36]; // transposed: [n][k]

  int mvalid = M - bm; if (mvalid > 128) mvalid = 128;
  int wv = mvalid - wm*64; wv = wv < 0 ? 0 : (wv > 64 ? 64 : wv);
  const int mfn = (wv + 15) >> 4;  // live 16-row fragments for this wave

  f32x4 acc[4][4];
  #pragma unroll
  for (int i = 0; i < 4; ++i)
    #pragma unroll
    for (int j = 0; j < 4; ++j)
      acc[i][j] = (f32x4){0.f, 0.f, 0.f, 0.f};

  const int arow = tid >> 3;          // 0..31
  const int acol = (tid & 7) << 2;    // 0..28
  const int brow = tid >> 5;          // 0..7
  const int bcol4 = (tid & 31) << 2;  // 0..124

  for (int kt = 0; kt < K; kt += 32){
    // ---- stage A (row-major, zero-pad M overflow) ----
    #pragma unroll
    for (int p = 0; p < 4; ++p){
      int r = p*32 + arow;
      float4 v = {0.f,0.f,0.f,0.f};
      if (bm + r < M) v = *(const float4*)(A + (long)(bm + r)*lda + kt + acol);
      us4 vh, vl; unsigned short hh, ll;
      split2(v.x, hh, ll); vh[0]=hh; vl[0]=ll;
      split2(v.y, hh, ll); vh[1]=hh; vl[1]=ll;
      split2(v.z, hh, ll); vh[2]=hh; vl[2]=ll;
      split2(v.w, hh, ll); vh[3]=hh; vl[3]=ll;
      *(us4*)&Ah[r][acol] = vh;
      *(us4*)&Al[r][acol] = vl;
    }
    // ---- stage B transposed ----
    #pragma unroll
    for (int p = 0; p < 4; ++p){
      int kk = p*8 + brow;
      float4 v = *(const float4*)(B + (long)(kt + kk)*ldb + bcol + bcol4);
      unsigned short hh, ll;
      split2(v.x, hh, ll); Bh[bcol4+0][kk]=hh; Bl[bcol4+0][kk]=ll;
      split2(v.y, hh, ll); Bh[bcol4+1][kk]=hh; Bl[bcol4+1][kk]=ll;
      split2(v.z, hh, ll); Bh[bcol4+2][kk]=hh; Bl[bcol4+2][kk]=ll;
      split2(v.w, hh, ll); Bh[bcol4+3][kk]=hh; Bl[bcol4+3][kk]=ll;
    }
    __syncthreads();

    Frag bh[4], bl[4];
    #pragma unroll
    for (int nf = 0; nf < 4; ++nf){
      const unsigned short* p0 = &Bh[wn*64 + nf*16 + r16][4*g];
      bh[nf].u[0] = *(const unsigned long long*)(p0);
      bh[nf].u[1] = *(const unsigned long long*)(p0 + 16);
      const unsigned short* p1 = &Bl[wn*64 + nf*16 + r16][4*g];
      bl[nf].u[0] = *(const unsigned long long*)(p1);
      bl[nf].u[1] = *(const unsigned long long*)(p1 + 16);
    }
    #pragma unroll
    for (int mf = 0; mf < 4; ++mf){
      if (mf < mfn){
        Frag ah, al;
        const unsigned short* p0 = &Ah[wm*64 + mf*16 + r16][4*g];
        ah.u[0] = *(const unsigned long long*)(p0);
        ah.u[1] = *(const unsigned long long*)(p0 + 16);
        const unsigned short* p1 = &Al[wm*64 + mf*16 + r16][4*g];
        al.u[0] = *(const unsigned long long*)(p1);
        al.u[1] = *(const unsigned long long*)(p1 + 16);
        #pragma unroll
        for (int nf = 0; nf < 4; ++nf){
          acc[mf][nf] = mf16(ah.s, bh[nf].s, acc[mf][nf]);
          acc[mf][nf] = mf16(ah.s, bl[nf].s, acc[mf][nf]);
          acc[mf][nf] = mf16(al.s, bh[nf].s, acc[mf][nf]);
        }
      }
    }
    __syncthreads();
  }

  // ---- epilogue: C/D layout col = lane&15, row = 4*(lane>>4)+reg ----
  #pragma unroll
  for (int mf = 0; mf < 4; ++mf){
    #pragma unroll
    for (int r = 0; r < 4; ++r){
      int grow = bm + wm*64 + mf*16 + 4*g + r;
      if (grow < M){
        #pragma unroll
        for (int nf = 0; nf < 4; ++nf){
          int gcol = bn + wn*64 + nf*16 + r16;
          float v = acc[mf][nf][r];
          if (BIAS) v += bias[gcol];
          if (RES)  v += res[(long)grow*ldres + gcol];
          C[(long)grow*ldc + gcol] = v;
        }
      }
    }
  }
}

// ---------------------------------------------------------------------------
// Fused dual attention. One block = (b, h, 64 q-rows). 4 waves x 16 q-rows.
// Text keys (77, padded to 96) via split-bf16 MFMA; softmax in registers from
// the MFMA D-layout; ip attention (4 keys) in fp32 vector, gated to b in {1,3}.
// LDS: K hi/lo [96][68] (union'd with P hi/lo [64][100]) + V^T hi/lo [64][100].
// ---------------------------------------------------------------------------
__global__ __launch_bounds__(256)
void attn_kernel(const float* __restrict__ Q,    // (4,4096,1280)
                 const float* __restrict__ kvt,  // (4,77,2560) [K|V]
                 const float* __restrict__ ipb,  // (4,4,2560)  [Kip|Vip]
                 float* __restrict__ attnb)      // (4,4096,1280)
{
  const int qt = blockIdx.x, h = blockIdx.y, b = blockIdx.z;
  const int tid = threadIdx.x, lane = tid & 63, w = tid >> 6;
  const int r16 = lane & 15, g = lane >> 4;
  const bool do_ip = (b & 1);
  const float scale = 0.125f;  // 1/sqrt(64)

  __shared__ unsigned short U0[96*68], U1[96*68];     // K hi/lo, then P hi/lo
  __shared__ unsigned short Vth[64*100], Vtl[64*100]; // V transposed [dv][j]
  __shared__ float ipk[4][64], ipv[4][64], pip[64][4];

  // ---- stage K (row-major) and V (transposed), zero-padded to 96 keys ----
  {
    int j  = tid >> 4;
    int d4 = (tid & 15) << 2;
    #pragma unroll
    for (int p = 0; p < 6; ++p){
      int jj = p*16 + j;
      float4 kv4 = {0.f,0.f,0.f,0.f}, vv4 = {0.f,0.f,0.f,0.f};
      if (jj < 77){
        const float* src = kvt + (long)(b*77 + jj)*2560 + h*64 + d4;
        kv4 = *(const float4*)(src);
        vv4 = *(const float4*)(src + 1280);
      }
      unsigned short hh, ll;
      us4 kh, kl;
      split2(kv4.x, hh, ll); kh[0]=hh; kl[0]=ll;
      split2(kv4.y, hh, ll); kh[1]=hh; kl[1]=ll;
      split2(kv4.z, hh, ll); kh[2]=hh; kl[2]=ll;
      split2(kv4.w, hh, ll); kh[3]=hh; kl[3]=ll;
      *(us4*)&U0[jj*68 + d4] = kh;
      *(us4*)&U1[jj*68 + d4] = kl;
      split2(vv4.x, hh, ll); Vth[(d4+0)*100 + jj]=hh; Vtl[(d4+0)*100 + jj]=ll;
      split2(vv4.y, hh, ll); Vth[(d4+1)*100 + jj]=hh; Vtl[(d4+1)*100 + jj]=ll;
      split2(vv4.z, hh, ll); Vth[(d4+2)*100 + jj]=hh; Vtl[(d4+2)*100 + jj]=ll;
      split2(vv4.w, hh, ll); Vth[(d4+3)*100 + jj]=hh; Vtl[(d4+3)*100 + jj]=ll;
    }
  }
  if (do_ip){
    int i = tid >> 6, d = tid & 63;
    const float* src = ipb + (long)(b*4 + i)*2560 + h*64 + d;
    ipk[i][d] = src[0];
    ipv[i][d] = src[1280];
  }
  __syncthreads();

  // ---- QK^T: A = Q (rows from global), B = K^T (from LDS) ----
  short8 qh[2], ql[2];
  {
    const float* qrow = Q + (long)(b*4096 + qt*64 + w*16 + r16)*1280 + h*64;
    #pragma unroll
    for (int ks = 0; ks < 2; ++ks){
      float4 a0 = *(const float4*)(qrow + ks*32 + 4*g);
      float4 a1 = *(const float4*)(qrow + ks*32 + 16 + 4*g);
      union { short8 s; unsigned short u[8]; } th, tl;
      unsigned short hh, ll;
      split2(a0.x, hh, ll); th.u[0]=hh; tl.u[0]=ll;
      split2(a0.y, hh, ll); th.u[1]=hh; tl.u[1]=ll;
      split2(a0.z, hh, ll); th.u[2]=hh; tl.u[2]=ll;
      split2(a0.w, hh, ll); th.u[3]=hh; tl.u[3]=ll;
      split2(a1.x, hh, ll); th.u[4]=hh; tl.u[4]=ll;
      split2(a1.y, hh, ll); th.u[5]=hh; tl.u[5]=ll;
      split2(a1.z, hh, ll); th.u[6]=hh; tl.u[6]=ll;
      split2(a1.w, hh, ll); th.u[7]=hh; tl.u[7]=ll;
      qh[ks] = th.s; ql[ks] = tl.s;
    }
  }
  f32x4 sacc[6];
  #pragma unroll
  for (int nf = 0; nf < 6; ++nf) sacc[nf] = (f32x4){0.f,0.f,0.f,0.f};
  #pragma unroll
  for (int nf = 0; nf < 6; ++nf){
    #pragma unroll
    for (int ks = 0; ks < 2; ++ks){
      Frag kh, kl;
      const unsigned short* p0 = &U0[(nf*16 + r16)*68 + ks*32 + 4*g];
      kh.u[0] = *(const unsigned long long*)(p0);
      kh.u[1] = *(const unsigned long long*)(p0 + 16);
      const unsigned short* p1 = &U1[(nf*16 + r16)*68 + ks*32 + 4*g];
      kl.u[0] = *(const unsigned long long*)(p1);
      kl.u[1] = *(const unsigned long long*)(p1 + 16);
      sacc[nf] = mf16(qh[ks], kh.s, sacc[nf]);
      sacc[nf] = mf16(qh[ks], kl.s, sacc[nf]);
      sacc[nf] = mf16(ql[ks], kh.s, sacc[nf]);
    }
  }

  // ---- softmax in registers (D-layout: col j = nf*16 + (lane&15), row = 4g+r)
  float mx[4] = {-1e30f,-1e30f,-1e30f,-1e30f};
  #pragma unroll
  for (int nf = 0; nf < 6; ++nf){
    if (nf*16 + r16 < 77){
      #pragma unroll
      for (int r = 0; r < 4; ++r) mx[r] = fmaxf(mx[r], sacc[nf][r]);
    }
  }
  #pragma unroll
  for (int off = 1; off < 16; off <<= 1){
    #pragma unroll
    for (int r = 0; r < 4; ++r) mx[r] = fmaxf(mx[r], __shfl_xor(mx[r], off));
  }
  float p[6][4];
  float sum[4] = {0.f,0.f,0.f,0.f};
  #pragma unroll
  for (int nf = 0; nf < 6; ++nf){
    bool valid = (nf*16 + r16 < 77);
    #pragma unroll
    for (int r = 0; r < 4; ++r){
      float e = valid ? __expf((sacc[nf][r] - mx[r]) * scale) : 0.f;
      p[nf][r] = e; sum[r] += e;
    }
  }
  #pragma unroll
  for (int off = 1; off < 16; off <<= 1){
    #pragma unroll
    for (int r = 0; r < 4; ++r) sum[r] += __shfl_xor(sum[r], off);
  }
  #pragma unroll
  for (int r = 0; r < 4; ++r) sum[r] = 1.f / sum[r];
  #pragma unroll
  for (int nf = 0; nf < 6; ++nf)
    #pragma unroll
    for (int r = 0; r < 4; ++r) p[nf][r] *= sum[r];

  // ---- ip attention scores (fp32 vector), 4 keys, per q-row ----
  if (do_ip){
    int rr = tid >> 2, ii = tid & 3;
    const float* q2 = Q + (long)(b*4096 + qt*64 + rr)*1280 + h*64;
    float s = 0.f;
    #pragma unroll
    for (int d4 = 0; d4 < 64; d4 += 4){
      float4 qv = *(const float4*)(q2 + d4);
      s += qv.x*ipk[ii][d4] + qv.y*ipk[ii][d4+1] + qv.z*ipk[ii][d4+2] + qv.w*ipk[ii][d4+3];
    }
    float m2 = fmaxf(s, __shfl_xor(s, 1)); m2 = fmaxf(m2, __shfl_xor(m2, 2));
    float e  = __expf((s - m2) * scale);
    float es = e + __shfl_xor(e, 1); es += __shfl_xor(es, 2);
    pip[rr][ii] = e / es;
  }

  __syncthreads();  // all K reads complete before P overwrites the union

  // ---- write P hi/lo into the K region ----
  #pragma unroll
  for (int nf = 0; nf < 6; ++nf){
    int jc = nf*16 + r16;
    #pragma unroll
    for (int r = 0; r < 4; ++r){
      int qr = w*16 + 4*g + r;
      unsigned short hh, ll; split2(p[nf][r], hh, ll);
      U0[qr*100 + jc] = hh; U1[qr*100 + jc] = ll;
    }
  }
  __syncthreads();

  // ---- PV: A = P (LDS), B = V (LDS, transposed) ----
  f32x4 oacc[4];
  #pragma unroll
  for (int nf = 0; nf < 4; ++nf) oacc[nf] = (f32x4){0.f,0.f,0.f,0.f};
  Frag ph[3], pl[3];
  #pragma unroll
  for (int ks = 0; ks < 3; ++ks){
    const unsigned short* p0 = &U0[(w*16 + r16)*100 + ks*32 + 4*g];
    ph[ks].u[0] = *(const unsigned long long*)(p0);
    ph[ks].u[1] = *(const unsigned long long*)(p0 + 16);
    const unsigned short* p1 = &U1[(w*16 + r16)*100 + ks*32 + 4*g];
    pl[ks].u[0] = *(const unsigned long long*)(p1);
    pl[ks].u[1] = *(const unsigned long long*)(p1 + 16);
  }
  #pragma unroll
  for (int nf = 0; nf < 4; ++nf){
    #pragma unroll
    for (int ks = 0; ks < 3; ++ks){
      Frag vh, vl;
      const unsigned short* p0 = &Vth[(nf*16 + r16)*100 + ks*32 + 4*g];
      vh.u[0] = *(const unsigned long long*)(p0);
      vh.u[1] = *(const unsigned long long*)(p0 + 16);
      const unsigned short* p1 = &Vtl[(nf*16 + r16)*100 + ks*32 + 4*g];
      vl.u[0] = *(const unsigned long long*)(p1);
      vl.u[1] = *(const unsigned long long*)(p1 + 16);
      oacc[nf] = mf16(ph[ks].s, vh.s, oacc[nf]);
      oacc[nf] = mf16(ph[ks].s, vl.s, oacc[nf]);
      oacc[nf] = mf16(pl[ks].s, vh.s, oacc[nf]);
    }
  }

  // ---- epilogue: + gated ip attention, write merged (b, q, h*64+dv) ----
  #pragma unroll
  for (int nf = 0; nf < 4; ++nf){
    int dv = nf*16 + r16;
    #pragma unroll
    for (int r = 0; r < 4; ++r){
      int lr = w*16 + 4*g + r;
      float val = oacc[nf][r];
      if (do_ip){
        val += pip[lr][0]*ipv[0][dv] + pip[lr][1]*ipv[1][dv]
             + pip[lr][2]*ipv[2][dv] + pip[lr][3]*ipv[3][dv];
      }
      attnb[(long)(b*4096 + qt*64 + lr)*1280 + h*64 + dv] = val;
    }
  }
}

// ---------------------------------------------------------------------------
extern "C" void kernel_launch(void* const* d_in, const int* in_sizes, int n_in,
                              void* d_out, int out_size, void* d_ws, size_t ws_size,
                              hipStream_t stream)
{
  const float* hs   = (const float*)d_in[0];  // (4,4096,1280)
  const float* ehs  = (const float*)d_in[1];  // (4,81,2048)
  const float* Wq   = (const float*)d_in[2];
  const float* Wk   = (const float*)d_in[3];
  const float* Wv   = (const float*)d_in[4];
  const float* Wkip = (const float*)d_in[5];
  const float* Wvip = (const float*)d_in[6];
  const float* Wout = (const float*)d_in[7];
  const float* bout = (const float*)d_in[8];
  float* out = (float*)d_out;
  float* ws  = (float*)d_ws;

  float* attnb = ws;                        // 16384*1280
  float* kvt   = attnb + 16384L*1280;       // 4*77*2560
  float* ipbuf = kvt + 4L*77*2560;          // 4*4*2560
  float* Qb    = out;                       // Q staged in d_out

  dim3 blk(256);
  const int BIGN = 1 << 30;

  // text K/V projection: per-batch (M=77) @ [Wk|Wv] (2048 x 2560)
  gemm_split<0,0><<<dim3(20,1,4), blk, 0, stream>>>(
      ehs, 2048, 81L*2048, 77, Wk, Wv, 1280, 1280,
      kvt, 2560, 77L*2560, 2048, nullptr, nullptr, 0);
  // ip K/V projection: per-batch (M=4) @ [Wk_ip|Wv_ip]
  gemm_split<0,0><<<dim3(20,1,4), blk, 0, stream>>>(
      ehs + 77L*2048, 2048, 81L*2048, 4, Wkip, Wvip, 1280, 1280,
      ipbuf, 2560, 4L*2560, 2048, nullptr, nullptr, 0);
  // Q projection: (16384 x 1280) @ Wq -> d_out (scratch)
  gemm_split<0,0><<<dim3(10,128,1), blk, 0, stream>>>(
      hs, 1280, 0, 16384, Wq, Wq, BIGN, 1280,
      Qb, 1280, 0, 1280, nullptr, nullptr, 0);
  // fused dual attention -> attnb
  attn_kernel<<<dim3(64,20,4), blk, 0, stream>>>(Qb, kvt, ipbuf, attnb);
  // output projection + bias + residual -> d_out
  gemm_split<1,1><<<dim3(10,128,1), blk, 0, stream>>>(
      attnb, 1280, 0, 16384, Wout, Wout, BIGN, 1280,
      out, 1280, 0, 1280, bout, hs, 1280);
}